// Round 1
// baseline (22112.013 us; speedup 1.0000x reference)
//
#include <hip/hip_runtime.h>
#include <cstdint>
#include <cstddef>

typedef __attribute__((ext_vector_type(8))) short short8;
typedef __attribute__((ext_vector_type(4))) float f32x4;

#define MFMA16(a, b, c) __builtin_amdgcn_mfma_f32_16x16x32_bf16((a), (b), (c), 0, 0, 0)

constexpr int kB = 512, kS = 256, kI = 12, kH = 256, kA = 9;
constexpr int kNS = 8;    // hidden slices per batch tile (32 h-units each)
constexpr int kNB = 32;   // batch tiles (16 rows each)
constexpr int LDH = 264;  // padded LDS stride (bf16) for K=256 operand tiles
constexpr int LDG = 132;  // padded LDS stride (fp32) for the 16x128 gate tile

// d_out layout (floats): [logits 512*9][h0 512*256][h1 512*256][c0 512*256][c1 512*256]
constexpr int OUT_H = kB * kA;              // 4608
constexpr int OUT_C = OUT_H + 2 * kB * kH;  // 266752

__device__ __forceinline__ short f2bf(float f) {  // RTNE fp32 -> bf16 bits
  uint32_t u = __float_as_uint(f);
  u += 0x7fffu + ((u >> 16) & 1u);
  return (short)(u >> 16);
}
__device__ __forceinline__ float fast_sigmoid(float v) {
  return __builtin_amdgcn_rcpf(1.f + __expf(-v));
}
__device__ __forceinline__ float fast_tanh(float v) {
  return 2.f * __builtin_amdgcn_rcpf(1.f + __expf(-2.f * v)) - 1.f;
}

// Persistent fused scan. Grid = 256 wgs (32 btiles x 8 slices), block = 256 (4 waves).
// wg (btile, slice) owns batch rows [btile*16, +16) and hidden units [slice*32, +32)
// of BOTH layers. Weight B-fragments live in registers (~256 VGPRs/lane).
// Cross-wg h broadcast: double-buffered global bf16 buffers + per-step monotonic
// flag counters (agent-scope release/acquire).
__global__ __launch_bounds__(256, 1) void lstm_scan_kernel(
    const float* __restrict__ x,
    const float* __restrict__ W_emb, const float* __restrict__ b_emb,
    const float* __restrict__ w_ih0, const float* __restrict__ w_hh0,
    const float* __restrict__ b_ih0, const float* __restrict__ b_hh0,
    const float* __restrict__ w_ih1, const float* __restrict__ w_hh1,
    const float* __restrict__ b_ih1, const float* __restrict__ b_hh1,
    unsigned short* __restrict__ h0ex, unsigned short* __restrict__ h1ex,
    int* __restrict__ flags0, int* __restrict__ flags1,
    float* __restrict__ dout)
{
  const int tid   = threadIdx.x;
  const int btile = blockIdx.x & (kNB - 1);  // bid%32 -> slices of a btile share an XCD
  const int slice = blockIdx.x >> 5;
  const int b0    = btile * 16;
  const int lane  = tid & 63;
  const int wave  = tid >> 6;
  const int n16   = lane & 15;
  const int quad  = lane >> 4;

  __shared__ short xlds[16 * 32];    // x_t tile, K padded 12->32 with zeros
  __shared__ short embL[16 * LDH];   // emb_t (bf16), A-operand for layer0 x-part
  __shared__ short hA[16 * LDH];     // h0 full (prev step, then y0_t for layer1)
  __shared__ short hB[16 * LDH];     // h1 full (prev step)
  __shared__ float gL[16 * LDG];     // gates 16 x 128 fp32

  // ---------------- one-time init ----------------
  for (int i = tid; i < 16 * 32; i += 256) xlds[i] = 0;
  for (int i = tid; i < 16 * LDH; i += 256) { hA[i] = 0; hB[i] = 0; }

  // Weight B-fragments: wave owns N-tiles {wave, wave+4} of the slice's 128 gate cols.
  // B layout for mfma_16x16x32_bf16: lane(n=lane&15, quad) holds B[k=quad*8+j][n],
  // i.e. 8 consecutive k from weight row `gate_col` (weights are [4H, H] row-major).
  const float* Wm[4] = { w_ih0, w_hh0, w_ih1, w_hh1 };
  short8 wB[2][4][8];
#pragma unroll
  for (int ti = 0; ti < 2; ++ti) {
    const int nt   = wave + ti * 4;
    const int gcol = (nt >> 1) * kH + slice * 32 + (nt & 1) * 16 + n16;
#pragma unroll
    for (int mat = 0; mat < 4; ++mat) {
      const float* wp = Wm[mat] + (size_t)gcol * kH;
#pragma unroll
      for (int kk = 0; kk < 8; ++kk) {
        const float* p = wp + kk * 32 + quad * 8;
        const float4 f0 = *(const float4*)p;
        const float4 f1 = *(const float4*)(p + 4);
        short8 v;
        v[0] = f2bf(f0.x); v[1] = f2bf(f0.y); v[2] = f2bf(f0.z); v[3] = f2bf(f0.w);
        v[4] = f2bf(f1.x); v[5] = f2bf(f1.y); v[6] = f2bf(f1.z); v[7] = f2bf(f1.w);
        wB[ti][mat][kk] = v;
      }
    }
  }
  // Embedding weights (K=12 zero-padded to 32). Wave computes emb cols [wave*64, +64).
  short8 wE[4];
  float bembv[4];
#pragma unroll
  for (int i = 0; i < 4; ++i) {
    const int col = wave * 64 + i * 16 + n16;
    short8 v;
#pragma unroll
    for (int j = 0; j < 8; ++j) {
      const int k = quad * 8 + j;
      v[j] = (k < kI) ? f2bf(W_emb[col * kI + k]) : (short)0;
    }
    wE[i] = v;
    bembv[i] = b_emb[col];
  }
  // Per-thread gate biases: thread = (m=tid&15, units {tid>>4, tid>>4+16}).
  const int m_ew = tid & 15;
  const int uu   = tid >> 4;
  float bi0[2][4], bi1[2][4];
#pragma unroll
  for (int s2 = 0; s2 < 2; ++s2) {
    const int col = slice * 32 + uu + s2 * 16;
#pragma unroll
    for (int g = 0; g < 4; ++g) {
      bi0[s2][g] = b_ih0[g * kH + col] + b_hh0[g * kH + col];
      bi1[s2][g] = b_ih1[g * kH + col] + b_hh1[g * kH + col];
    }
  }
  float c0v[2] = {0.f, 0.f}, c1v[2] = {0.f, 0.f};

  __syncthreads();

  int* const f0base = flags0 + btile;
  int* const f1base = flags1 + btile;

  for (int t = 0; t < kS; ++t) {
    // -------- stage x_t (16 rows x 12) --------
    if (tid < 192) {
      const int mr = tid / kI, kc = tid - (tid / kI) * kI;
      xlds[mr * 32 + kc] = f2bf(x[((size_t)(b0 + mr) * kS + t) * kI + kc]);
    }
    __syncthreads();
    // -------- emb_t = relu(x_t @ W_emb^T + b_emb), MFMA K=32 zero-padded --------
    {
      const short8 xa = *(const short8*)&xlds[n16 * 32 + quad * 8];
#pragma unroll
      for (int i = 0; i < 4; ++i) {
        f32x4 z = {0.f, 0.f, 0.f, 0.f};
        f32x4 e = MFMA16(xa, wE[i], z);
        const int col = wave * 64 + i * 16 + n16;
#pragma unroll
        for (int r = 0; r < 4; ++r) {
          float v = e[r] + bembv[i];
          v = v > 0.f ? v : 0.f;
          embL[(quad * 4 + r) * LDH + col] = f2bf(v);  // C-layout: row=quad*4+r, col=n
        }
      }
    }
    __syncthreads();
    // -------- layer-0 gates: emb_t @ w_ih0^T + h0_{t-1} @ w_hh0^T --------
    {
      f32x4 acc0 = {0.f, 0.f, 0.f, 0.f}, acc1 = {0.f, 0.f, 0.f, 0.f};
#pragma unroll
      for (int kk = 0; kk < 8; ++kk) {
        const short8 a = *(const short8*)&embL[n16 * LDH + kk * 32 + quad * 8];
        acc0 = MFMA16(a, wB[0][0][kk], acc0);
        acc1 = MFMA16(a, wB[1][0][kk], acc1);
      }
#pragma unroll
      for (int kk = 0; kk < 8; ++kk) {
        const short8 a = *(const short8*)&hA[n16 * LDH + kk * 32 + quad * 8];
        acc0 = MFMA16(a, wB[0][1][kk], acc0);
        acc1 = MFMA16(a, wB[1][1][kk], acc1);
      }
#pragma unroll
      for (int ti = 0; ti < 2; ++ti) {
        const int nt = wave + ti * 4;
        const int lcol = (nt >> 1) * 32 + (nt & 1) * 16 + n16;
        const f32x4 a = ti ? acc1 : acc0;
#pragma unroll
        for (int r = 0; r < 4; ++r) gL[(quad * 4 + r) * LDG + lcol] = a[r];
      }
    }
    __syncthreads();
    // -------- layer-0 elementwise (fp32 state) --------
#pragma unroll
    for (int s2 = 0; s2 < 2; ++s2) {
      const int u = uu + s2 * 16;
      const float iv = gL[m_ew * LDG +       u] + bi0[s2][0];
      const float fv = gL[m_ew * LDG +  32 + u] + bi0[s2][1];
      const float gv = gL[m_ew * LDG +  64 + u] + bi0[s2][2];
      const float ov = gL[m_ew * LDG +  96 + u] + bi0[s2][3];
      const float c = fast_sigmoid(fv) * c0v[s2] + fast_sigmoid(iv) * fast_tanh(gv);
      c0v[s2] = c;
      const float h = fast_sigmoid(ov) * fast_tanh(c);
      const int col = slice * 32 + u;
      h0ex[(size_t)(t & 1) * (kB * kH) + (size_t)(b0 + m_ew) * kH + col] =
          (unsigned short)f2bf(h);
      if (t == kS - 1) {
        dout[OUT_H + (size_t)(b0 + m_ew) * kH + col] = h;
        dout[OUT_C + (size_t)(b0 + m_ew) * kH + col] = c;
      }
    }
    __threadfence();
    __syncthreads();
    if (tid == 0)
      __hip_atomic_fetch_add(f0base + t * kNB, 1, __ATOMIC_RELEASE, __HIP_MEMORY_SCOPE_AGENT);
    // -------- wait: full y0_t (this step) and full h1_{t-1} --------
    if (tid == 0) {
      while (__hip_atomic_load(f0base + t * kNB, __ATOMIC_ACQUIRE, __HIP_MEMORY_SCOPE_AGENT) < kNS)
        __builtin_amdgcn_s_sleep(1);
      if (t > 0)
        while (__hip_atomic_load(f1base + (t - 1) * kNB, __ATOMIC_ACQUIRE, __HIP_MEMORY_SCOPE_AGENT) < kNS)
          __builtin_amdgcn_s_sleep(1);
    }
    __syncthreads();
    __threadfence();  // acquire ordering + L1 inval for every reading thread
    // -------- stage hA = y0_t, hB = h1_{t-1} (16 x 256 bf16 each) --------
    {
      const int row = tid >> 4, c16 = (tid & 15) * 16;
      const uint4* s0 = (const uint4*)&h0ex[(size_t)(t & 1) * (kB * kH) + (size_t)(b0 + row) * kH + c16];
      const uint4 v0 = s0[0], v1 = s0[1];
      *(uint4*)&hA[row * LDH + c16]     = v0;
      *(uint4*)&hA[row * LDH + c16 + 8] = v1;
      if (t > 0) {
        const uint4* s1 = (const uint4*)&h1ex[(size_t)((t - 1) & 1) * (kB * kH) + (size_t)(b0 + row) * kH + c16];
        const uint4 w0 = s1[0], w1v = s1[1];
        *(uint4*)&hB[row * LDH + c16]     = w0;
        *(uint4*)&hB[row * LDH + c16 + 8] = w1v;
      }
    }
    __syncthreads();
    // -------- layer-1 gates: y0_t @ w_ih1^T + h1_{t-1} @ w_hh1^T --------
    {
      f32x4 acc0 = {0.f, 0.f, 0.f, 0.f}, acc1 = {0.f, 0.f, 0.f, 0.f};
#pragma unroll
      for (int kk = 0; kk < 8; ++kk) {
        const short8 a = *(const short8*)&hA[n16 * LDH + kk * 32 + quad * 8];
        acc0 = MFMA16(a, wB[0][2][kk], acc0);
        acc1 = MFMA16(a, wB[1][2][kk], acc1);
      }
#pragma unroll
      for (int kk = 0; kk < 8; ++kk) {
        const short8 a = *(const short8*)&hB[n16 * LDH + kk * 32 + quad * 8];
        acc0 = MFMA16(a, wB[0][3][kk], acc0);
        acc1 = MFMA16(a, wB[1][3][kk], acc1);
      }
#pragma unroll
      for (int ti = 0; ti < 2; ++ti) {
        const int nt = wave + ti * 4;
        const int lcol = (nt >> 1) * 32 + (nt & 1) * 16 + n16;
        const f32x4 a = ti ? acc1 : acc0;
#pragma unroll
        for (int r = 0; r < 4; ++r) gL[(quad * 4 + r) * LDG + lcol] = a[r];
      }
    }
    __syncthreads();
    // -------- layer-1 elementwise --------
#pragma unroll
    for (int s2 = 0; s2 < 2; ++s2) {
      const int u = uu + s2 * 16;
      const float iv = gL[m_ew * LDG +       u] + bi1[s2][0];
      const float fv = gL[m_ew * LDG +  32 + u] + bi1[s2][1];
      const float gv = gL[m_ew * LDG +  64 + u] + bi1[s2][2];
      const float ov = gL[m_ew * LDG +  96 + u] + bi1[s2][3];
      const float c = fast_sigmoid(fv) * c1v[s2] + fast_sigmoid(iv) * fast_tanh(gv);
      c1v[s2] = c;
      const float h = fast_sigmoid(ov) * fast_tanh(c);
      const int col = slice * 32 + u;
      h1ex[(size_t)(t & 1) * (kB * kH) + (size_t)(b0 + m_ew) * kH + col] =
          (unsigned short)f2bf(h);
      if (t == kS - 1) {
        dout[OUT_H + kB * kH + (size_t)(b0 + m_ew) * kH + col] = h;
        dout[OUT_C + kB * kH + (size_t)(b0 + m_ew) * kH + col] = c;
      }
    }
    __threadfence();
    __syncthreads();
    if (tid == 0)
      __hip_atomic_fetch_add(f1base + t * kNB, 1, __ATOMIC_RELEASE, __HIP_MEMORY_SCOPE_AGENT);
  }
}

// LayerNorm + MLP head, exact fp32. One wave per batch row.
__global__ __launch_bounds__(64) void head_kernel(
    const float* __restrict__ h1last, const float* __restrict__ mask,
    const float* __restrict__ ln_g, const float* __restrict__ ln_b,
    const float* __restrict__ w1, const float* __restrict__ b1,
    const float* __restrict__ w2, const float* __restrict__ b2,
    float* __restrict__ out)
{
  const int r = blockIdx.x;
  const int lane = threadIdx.x;
  __shared__ float ns[kH];
  __shared__ float hd[32];
  const float4 v = *(const float4*)&h1last[r * kH + lane * 4];
  float vv[4] = {v.x, v.y, v.z, v.w};
  float s = vv[0] + vv[1] + vv[2] + vv[3];
#pragma unroll
  for (int off = 32; off > 0; off >>= 1) s += __shfl_xor(s, off, 64);
  const float mean = s * (1.f / kH);
  float q = 0.f;
#pragma unroll
  for (int j = 0; j < 4; ++j) { const float d = vv[j] - mean; q += d * d; }
#pragma unroll
  for (int off = 32; off > 0; off >>= 1) q += __shfl_xor(q, off, 64);
  const float rstd = rsqrtf(q * (1.f / kH) + 1e-5f);
#pragma unroll
  for (int j = 0; j < 4; ++j) {
    const int c = lane * 4 + j;
    ns[c] = (vv[j] - mean) * rstd * ln_g[c] + ln_b[c];
  }
  __syncthreads();
  if (lane < 32) {
    float a = b1[lane];
    const float* wr = w1 + lane * kH;
    for (int k = 0; k < kH; ++k) a += ns[k] * wr[k];
    hd[lane] = a > 0.f ? a : 0.f;
  }
  __syncthreads();
  if (lane < kA) {
    float a = b2[lane];
    const float* wr = w2 + lane * 32;
#pragma unroll
    for (int k = 0; k < 32; ++k) a += hd[k] * wr[k];
    a += (1.f - mask[r * kA + lane]) * (-1e9f);
    out[r * kA + lane] = a;
  }
}

extern "C" void kernel_launch(void* const* d_in, const int* in_sizes, int n_in,
                              void* d_out, int out_size, void* d_ws, size_t ws_size,
                              hipStream_t stream)
{
  (void)in_sizes; (void)n_in; (void)out_size; (void)ws_size;
  const float* x     = (const float*)d_in[0];
  const float* mask  = (const float*)d_in[1];
  const float* W_emb = (const float*)d_in[2];
  const float* b_emb = (const float*)d_in[3];
  const float* w_ih0 = (const float*)d_in[4];
  const float* w_hh0 = (const float*)d_in[5];
  const float* b_ih0 = (const float*)d_in[6];
  const float* b_hh0 = (const float*)d_in[7];
  const float* w_ih1 = (const float*)d_in[8];
  const float* w_hh1 = (const float*)d_in[9];
  const float* b_ih1 = (const float*)d_in[10];
  const float* b_hh1 = (const float*)d_in[11];
  const float* ln_g  = (const float*)d_in[12];
  const float* ln_b  = (const float*)d_in[13];
  const float* w1    = (const float*)d_in[14];
  const float* b1    = (const float*)d_in[15];
  const float* w2    = (const float*)d_in[16];
  const float* b2    = (const float*)d_in[17];
  float* out = (float*)d_out;

  // ws layout: h0ex[2][512][256] bf16 | h1ex[2][512][256] bf16 | flags0[256][32] | flags1[256][32]
  unsigned short* h0ex = (unsigned short*)d_ws;
  unsigned short* h1ex = h0ex + 2 * kB * kH;
  const size_t exch_bytes = (size_t)2 * (2 * kB * kH) * sizeof(unsigned short);  // 1 MiB
  int* flags0 = (int*)((char*)d_ws + exch_bytes);
  int* flags1 = flags0 + kS * kNB;
  const size_t flag_bytes = (size_t)2 * kS * kNB * sizeof(int);  // 64 KiB

  hipMemsetAsync(d_ws, 0, exch_bytes + flag_bytes, stream);

  lstm_scan_kernel<<<dim3(kNB * kNS), dim3(256), 0, stream>>>(
      x, W_emb, b_emb, w_ih0, w_hh0, b_ih0, b_hh0, w_ih1, w_hh1, b_ih1, b_hh1,
      h0ex, h1ex, flags0, flags1, out);

  head_kernel<<<dim3(kB), dim3(64), 0, stream>>>(
      out + OUT_H + kB * kH, mask, ln_g, ln_b, w1, b1, w2, b2, out);
}

// Round 2
// 1157.420 us; speedup vs baseline: 19.1046x; 19.1046x over previous
//
#include <hip/hip_runtime.h>
#include <cstdint>
#include <cstddef>

typedef __attribute__((ext_vector_type(8))) short short8;
typedef __attribute__((ext_vector_type(4))) float f32x4;

#define MFMA16(a, b, c) __builtin_amdgcn_mfma_f32_16x16x32_bf16((a), (b), (c), 0, 0, 0)

constexpr int kB = 512, kS = 256, kI = 12, kH = 256, kA = 9;
constexpr int kNS = 8;    // hidden slices per batch tile (32 h-units each)
constexpr int kNB = 32;   // batch tiles (16 rows each)
constexpr int LDH = 264;  // padded LDS stride (bf16) for K=256 operand tiles
constexpr int LDG = 132;  // padded LDS stride (fp32) for the 16x128 gate tile
constexpr int kBH = kB * kH;

// d_out layout (floats): [logits 512*9][h0 512*256][h1 512*256][c0 512*256][c1 512*256]
constexpr int OUT_H = kB * kA;              // 4608
constexpr int OUT_C = OUT_H + 2 * kB * kH;  // 266752

__device__ __forceinline__ short f2bf(float f) {  // RTNE fp32 -> bf16 bits
  uint32_t u = __float_as_uint(f);
  u += 0x7fffu + ((u >> 16) & 1u);
  return (short)(u >> 16);
}
__device__ __forceinline__ float fast_sigmoid(float v) {
  return __builtin_amdgcn_rcpf(1.f + __expf(-v));
}
__device__ __forceinline__ float fast_tanh(float v) {
  return 2.f * __builtin_amdgcn_rcpf(1.f + __expf(-2.f * v)) - 1.f;
}

// Persistent fused scan. Grid = 256 wgs (32 btiles x 8 slices), block = 256 (4 waves).
// NO fences / NO acquire-release (those emit bulk buffer_wbl2/buffer_inv on gfx950 —
// measured 22 ms of whole-L2 maintenance). All cross-wg traffic = RELAXED agent-scope
// atomics (per-access sc1, coherent at the Infinity Cache). Ordering: __syncthreads()
// drains vmcnt(0) before s_barrier, so data stores are IC-visible before the flag add.
__global__ __launch_bounds__(256, 1) void lstm_scan_kernel(
    const float* __restrict__ x,
    const float* __restrict__ W_emb, const float* __restrict__ b_emb,
    const float* __restrict__ w_ih0, const float* __restrict__ w_hh0,
    const float* __restrict__ b_ih0, const float* __restrict__ b_hh0,
    const float* __restrict__ w_ih1, const float* __restrict__ w_hh1,
    const float* __restrict__ b_ih1, const float* __restrict__ b_hh1,
    unsigned short* __restrict__ h0ex, unsigned short* __restrict__ h1ex,
    int* __restrict__ flags0, int* __restrict__ flags1,
    float* __restrict__ dout)
{
  const int tid   = threadIdx.x;
  const int btile = blockIdx.x & (kNB - 1);  // bid%32 -> slices of a btile share an XCD
  const int slice = blockIdx.x >> 5;
  const int b0    = btile * 16;
  const int lane  = tid & 63;
  const int wave  = tid >> 6;
  const int n16   = lane & 15;
  const int quad  = lane >> 4;

  __shared__ short xlds[16 * 32];    // x_t tile, K padded 12->32 with zeros
  __shared__ short embL[16 * LDH];   // emb_t (bf16), A-operand for layer0 x-part
  __shared__ short hA[16 * LDH];     // h0 full (prev step h0, then y0_t after exchange)
  __shared__ short hB[16 * LDH];     // h1 full (prev step)
  __shared__ float gL[16 * LDG];     // gates 16 x 128 fp32

  // ---------------- one-time init ----------------
  for (int i = tid; i < 16 * 32; i += 256) xlds[i] = 0;
  for (int i = tid; i < 16 * LDH; i += 256) { hA[i] = 0; hB[i] = 0; }

  // Weight B-fragments in registers: wave owns N-tiles {wave, wave+4} of the slice's
  // 128 gate cols. B layout for mfma_16x16x32_bf16: lane(n=lane&15, quad) holds
  // B[k=quad*8+j][n] = weight row `gate_col`, k-slice (weights are [4H, H] row-major).
  const float* Wm[4] = { w_ih0, w_hh0, w_ih1, w_hh1 };
  short8 wB[2][4][8];
#pragma unroll
  for (int ti = 0; ti < 2; ++ti) {
    const int nt   = wave + ti * 4;
    const int gcol = (nt >> 1) * kH + slice * 32 + (nt & 1) * 16 + n16;
#pragma unroll
    for (int mat = 0; mat < 4; ++mat) {
      const float* wp = Wm[mat] + (size_t)gcol * kH;
#pragma unroll
      for (int kk = 0; kk < 8; ++kk) {
        const float* p = wp + kk * 32 + quad * 8;
        const float4 f0 = *(const float4*)p;
        const float4 f1 = *(const float4*)(p + 4);
        short8 v;
        v[0] = f2bf(f0.x); v[1] = f2bf(f0.y); v[2] = f2bf(f0.z); v[3] = f2bf(f0.w);
        v[4] = f2bf(f1.x); v[5] = f2bf(f1.y); v[6] = f2bf(f1.z); v[7] = f2bf(f1.w);
        wB[ti][mat][kk] = v;
      }
    }
  }
  // Embedding weights (K=12 zero-padded to 32). Wave computes emb cols [wave*64, +64).
  short8 wE[4];
  float bembv[4];
#pragma unroll
  for (int i = 0; i < 4; ++i) {
    const int col = wave * 64 + i * 16 + n16;
    short8 v;
#pragma unroll
    for (int j = 0; j < 8; ++j) {
      const int k = quad * 8 + j;
      v[j] = (k < kI) ? f2bf(W_emb[col * kI + k]) : (short)0;
    }
    wE[i] = v;
    bembv[i] = b_emb[col];
  }
  // Elementwise thread mapping: thread = (m=tid&15, col pair {2p, 2p+1}), p=tid>>4.
  const int m_ew = tid & 15;
  const int p2   = (tid >> 4) * 2;
  float bi0[2][4], bi1[2][4];
#pragma unroll
  for (int j = 0; j < 2; ++j) {
    const int col = slice * 32 + p2 + j;
#pragma unroll
    for (int g = 0; g < 4; ++g) {
      bi0[j][g] = b_ih0[g * kH + col] + b_hh0[g * kH + col];
      bi1[j][g] = b_ih1[g * kH + col] + b_hh1[g * kH + col];
    }
  }
  float c0v[2] = {0.f, 0.f}, c1v[2] = {0.f, 0.f};

  const int mr = tid / kI, kc = tid - (tid / kI) * kI;  // x staging map (tid<192)

  __syncthreads();

  // -------- pre-loop: stage x_0, compute emb_0 --------
  if (tid < 192) xlds[mr * 32 + kc] = f2bf(x[((size_t)(b0 + mr) * kS + 0) * kI + kc]);
  __syncthreads();
  {
    const short8 xa = *(const short8*)&xlds[n16 * 32 + quad * 8];
#pragma unroll
    for (int i = 0; i < 4; ++i) {
      f32x4 z = {0.f, 0.f, 0.f, 0.f};
      f32x4 e = MFMA16(xa, wE[i], z);
      const int col = wave * 64 + i * 16 + n16;
#pragma unroll
      for (int r = 0; r < 4; ++r) {
        float v = e[r] + bembv[i];
        v = v > 0.f ? v : 0.f;
        embL[(quad * 4 + r) * LDH + col] = f2bf(v);
      }
    }
  }
  __syncthreads();

  int* const f0base = flags0 + (size_t)btile * kS;
  int* const f1base = flags1 + (size_t)btile * kS;

  for (int t = 0; t < kS; ++t) {
    // -------- p0: prefetch x_{t+1} (plain load; input is read-only) --------
    float xreg = 0.f;
    if (t + 1 < kS && tid < 192)
      xreg = x[((size_t)(b0 + mr) * kS + (t + 1)) * kI + kc];

    // -------- p1: layer-0 gates = emb_t @ w_ih0^T + h0_{t-1} @ w_hh0^T --------
    {
      f32x4 acc0 = {0.f, 0.f, 0.f, 0.f}, acc1 = {0.f, 0.f, 0.f, 0.f};
#pragma unroll
      for (int kk = 0; kk < 8; ++kk) {
        const short8 a = *(const short8*)&embL[n16 * LDH + kk * 32 + quad * 8];
        acc0 = MFMA16(a, wB[0][0][kk], acc0);
        acc1 = MFMA16(a, wB[1][0][kk], acc1);
      }
#pragma unroll
      for (int kk = 0; kk < 8; ++kk) {
        const short8 a = *(const short8*)&hA[n16 * LDH + kk * 32 + quad * 8];
        acc0 = MFMA16(a, wB[0][1][kk], acc0);
        acc1 = MFMA16(a, wB[1][1][kk], acc1);
      }
#pragma unroll
      for (int ti = 0; ti < 2; ++ti) {
        const int nt = wave + ti * 4;
        const int lcol = (nt >> 1) * 32 + (nt & 1) * 16 + n16;
        const f32x4 a = ti ? acc1 : acc0;
#pragma unroll
        for (int r = 0; r < 4; ++r) gL[(quad * 4 + r) * LDG + lcol] = a[r];
      }
    }
    __syncthreads();

    // -------- p2: layer-0 elementwise (fp32 state), packed relaxed store --------
    {
      float hj[2];
#pragma unroll
      for (int j = 0; j < 2; ++j) {
        const int u = p2 + j;
        const float iv = gL[m_ew * LDG +       u] + bi0[j][0];
        const float fv = gL[m_ew * LDG +  32 + u] + bi0[j][1];
        const float gv = gL[m_ew * LDG +  64 + u] + bi0[j][2];
        const float ov = gL[m_ew * LDG +  96 + u] + bi0[j][3];
        const float c = fast_sigmoid(fv) * c0v[j] + fast_sigmoid(iv) * fast_tanh(gv);
        c0v[j] = c;
        hj[j] = fast_sigmoid(ov) * fast_tanh(c);
      }
      const uint32_t pk = (uint32_t)(uint16_t)f2bf(hj[0]) |
                          ((uint32_t)(uint16_t)f2bf(hj[1]) << 16);
      uint32_t* dst = (uint32_t*)&h0ex[(size_t)(t & 1) * kBH + (size_t)(b0 + m_ew) * kH + slice * 32 + p2];
      __hip_atomic_store(dst, pk, __ATOMIC_RELAXED, __HIP_MEMORY_SCOPE_AGENT);
      if (t == kS - 1) {
#pragma unroll
        for (int j = 0; j < 2; ++j) {
          const int col = slice * 32 + p2 + j;
          dout[OUT_H + (size_t)(b0 + m_ew) * kH + col] = hj[j];
          dout[OUT_C + (size_t)(b0 + m_ew) * kH + col] = c0v[j];
        }
      }
    }
    __syncthreads();  // drains vmcnt(0): h0 stores are IC-visible past this point

    // -------- p3: publish layer-0 slice --------
    if (tid == 0)
      __hip_atomic_fetch_add(f0base + t, 1, __ATOMIC_RELAXED, __HIP_MEMORY_SCOPE_AGENT);

    // -------- p4: emb_{t+1} (overlaps flag/data propagation through IC) --------
    if (t + 1 < kS) {
      if (tid < 192) xlds[mr * 32 + kc] = f2bf(xreg);
      __syncthreads();
      const short8 xa = *(const short8*)&xlds[n16 * 32 + quad * 8];
#pragma unroll
      for (int i = 0; i < 4; ++i) {
        f32x4 z = {0.f, 0.f, 0.f, 0.f};
        f32x4 e = MFMA16(xa, wE[i], z);
        const int col = wave * 64 + i * 16 + n16;
#pragma unroll
        for (int r = 0; r < 4; ++r) {
          float v = e[r] + bembv[i];
          v = v > 0.f ? v : 0.f;
          embL[(quad * 4 + r) * LDH + col] = f2bf(v);
        }
      }
    }

    // -------- p5: single wait point: full y0_t and full h1_{t-1} --------
    if (tid == 0) {
      while (__hip_atomic_load(f0base + t, __ATOMIC_RELAXED, __HIP_MEMORY_SCOPE_AGENT) < kNS)
        __builtin_amdgcn_s_sleep(1);
      if (t > 0)
        while (__hip_atomic_load(f1base + (t - 1), __ATOMIC_RELAXED, __HIP_MEMORY_SCOPE_AGENT) < kNS)
          __builtin_amdgcn_s_sleep(1);
    }
    __syncthreads();

    // -------- p7: gather full h0_t -> hA, h1_{t-1} -> hB (relaxed u64 loads) --------
    {
      const int rr = tid >> 4;
      const int cc = (tid & 15) * 16;
      const uint64_t* s0 = (const uint64_t*)&h0ex[(size_t)(t & 1) * kBH + (size_t)(b0 + rr) * kH + cc];
      uint64_t a0 = __hip_atomic_load(s0 + 0, __ATOMIC_RELAXED, __HIP_MEMORY_SCOPE_AGENT);
      uint64_t a1 = __hip_atomic_load(s0 + 1, __ATOMIC_RELAXED, __HIP_MEMORY_SCOPE_AGENT);
      uint64_t a2 = __hip_atomic_load(s0 + 2, __ATOMIC_RELAXED, __HIP_MEMORY_SCOPE_AGENT);
      uint64_t a3 = __hip_atomic_load(s0 + 3, __ATOMIC_RELAXED, __HIP_MEMORY_SCOPE_AGENT);
      uint64_t* dA = (uint64_t*)&hA[rr * LDH + cc];
      dA[0] = a0; dA[1] = a1; dA[2] = a2; dA[3] = a3;
      if (t > 0) {
        const uint64_t* s1 = (const uint64_t*)&h1ex[(size_t)((t - 1) & 1) * kBH + (size_t)(b0 + rr) * kH + cc];
        uint64_t b0v = __hip_atomic_load(s1 + 0, __ATOMIC_RELAXED, __HIP_MEMORY_SCOPE_AGENT);
        uint64_t b1v = __hip_atomic_load(s1 + 1, __ATOMIC_RELAXED, __HIP_MEMORY_SCOPE_AGENT);
        uint64_t b2v = __hip_atomic_load(s1 + 2, __ATOMIC_RELAXED, __HIP_MEMORY_SCOPE_AGENT);
        uint64_t b3v = __hip_atomic_load(s1 + 3, __ATOMIC_RELAXED, __HIP_MEMORY_SCOPE_AGENT);
        uint64_t* dB = (uint64_t*)&hB[rr * LDH + cc];
        dB[0] = b0v; dB[1] = b1v; dB[2] = b2v; dB[3] = b3v;
      }
    }
    __syncthreads();

    // -------- p8: layer-1 gates = y0_t @ w_ih1^T + h1_{t-1} @ w_hh1^T --------
    {
      f32x4 acc0 = {0.f, 0.f, 0.f, 0.f}, acc1 = {0.f, 0.f, 0.f, 0.f};
#pragma unroll
      for (int kk = 0; kk < 8; ++kk) {
        const short8 a = *(const short8*)&hA[n16 * LDH + kk * 32 + quad * 8];
        acc0 = MFMA16(a, wB[0][2][kk], acc0);
        acc1 = MFMA16(a, wB[1][2][kk], acc1);
      }
#pragma unroll
      for (int kk = 0; kk < 8; ++kk) {
        const short8 a = *(const short8*)&hB[n16 * LDH + kk * 32 + quad * 8];
        acc0 = MFMA16(a, wB[0][3][kk], acc0);
        acc1 = MFMA16(a, wB[1][3][kk], acc1);
      }
#pragma unroll
      for (int ti = 0; ti < 2; ++ti) {
        const int nt = wave + ti * 4;
        const int lcol = (nt >> 1) * 32 + (nt & 1) * 16 + n16;
        const f32x4 a = ti ? acc1 : acc0;
#pragma unroll
        for (int r = 0; r < 4; ++r) gL[(quad * 4 + r) * LDG + lcol] = a[r];
      }
    }
    __syncthreads();

    // -------- p9: layer-1 elementwise, packed relaxed store --------
    {
      float hj[2];
#pragma unroll
      for (int j = 0; j < 2; ++j) {
        const int u = p2 + j;
        const float iv = gL[m_ew * LDG +       u] + bi1[j][0];
        const float fv = gL[m_ew * LDG +  32 + u] + bi1[j][1];
        const float gv = gL[m_ew * LDG +  64 + u] + bi1[j][2];
        const float ov = gL[m_ew * LDG +  96 + u] + bi1[j][3];
        const float c = fast_sigmoid(fv) * c1v[j] + fast_sigmoid(iv) * fast_tanh(gv);
        c1v[j] = c;
        hj[j] = fast_sigmoid(ov) * fast_tanh(c);
      }
      const uint32_t pk = (uint32_t)(uint16_t)f2bf(hj[0]) |
                          ((uint32_t)(uint16_t)f2bf(hj[1]) << 16);
      uint32_t* dst = (uint32_t*)&h1ex[(size_t)(t & 1) * kBH + (size_t)(b0 + m_ew) * kH + slice * 32 + p2];
      __hip_atomic_store(dst, pk, __ATOMIC_RELAXED, __HIP_MEMORY_SCOPE_AGENT);
      if (t == kS - 1) {
#pragma unroll
        for (int j = 0; j < 2; ++j) {
          const int col = slice * 32 + p2 + j;
          dout[OUT_H + kBH + (size_t)(b0 + m_ew) * kH + col] = hj[j];
          dout[OUT_C + kBH + (size_t)(b0 + m_ew) * kH + col] = c1v[j];
        }
      }
    }
    __syncthreads();  // drains vmcnt(0) before flag publish

    // -------- p10: publish layer-1 slice (waited on at t+1's p5) --------
    if (tid == 0)
      __hip_atomic_fetch_add(f1base + t, 1, __ATOMIC_RELAXED, __HIP_MEMORY_SCOPE_AGENT);
  }
}

// LayerNorm + MLP head, exact fp32. One wave per batch row.
__global__ __launch_bounds__(64) void head_kernel(
    const float* __restrict__ h1last, const float* __restrict__ mask,
    const float* __restrict__ ln_g, const float* __restrict__ ln_b,
    const float* __restrict__ w1, const float* __restrict__ b1,
    const float* __restrict__ w2, const float* __restrict__ b2,
    float* __restrict__ out)
{
  const int r = blockIdx.x;
  const int lane = threadIdx.x;
  __shared__ float ns[kH];
  __shared__ float hd[32];
  const float4 v = *(const float4*)&h1last[r * kH + lane * 4];
  float vv[4] = {v.x, v.y, v.z, v.w};
  float s = vv[0] + vv[1] + vv[2] + vv[3];
#pragma unroll
  for (int off = 32; off > 0; off >>= 1) s += __shfl_xor(s, off, 64);
  const float mean = s * (1.f / kH);
  float q = 0.f;
#pragma unroll
  for (int j = 0; j < 4; ++j) { const float d = vv[j] - mean; q += d * d; }
#pragma unroll
  for (int off = 32; off > 0; off >>= 1) q += __shfl_xor(q, off, 64);
  const float rstd = rsqrtf(q * (1.f / kH) + 1e-5f);
#pragma unroll
  for (int j = 0; j < 4; ++j) {
    const int c = lane * 4 + j;
    ns[c] = (vv[j] - mean) * rstd * ln_g[c] + ln_b[c];
  }
  __syncthreads();
  if (lane < 32) {
    float a = b1[lane];
    const float* wr = w1 + lane * kH;
    for (int k = 0; k < kH; ++k) a += ns[k] * wr[k];
    hd[lane] = a > 0.f ? a : 0.f;
  }
  __syncthreads();
  if (lane < kA) {
    float a = b2[lane];
    const float* wr = w2 + lane * 32;
#pragma unroll
    for (int k = 0; k < 32; ++k) a += hd[k] * wr[k];
    a += (1.f - mask[r * kA + lane]) * (-1e9f);
    out[r * kA + lane] = a;
  }
}

extern "C" void kernel_launch(void* const* d_in, const int* in_sizes, int n_in,
                              void* d_out, int out_size, void* d_ws, size_t ws_size,
                              hipStream_t stream)
{
  (void)in_sizes; (void)n_in; (void)out_size; (void)ws_size;
  const float* x     = (const float*)d_in[0];
  const float* mask  = (const float*)d_in[1];
  const float* W_emb = (const float*)d_in[2];
  const float* b_emb = (const float*)d_in[3];
  const float* w_ih0 = (const float*)d_in[4];
  const float* w_hh0 = (const float*)d_in[5];
  const float* b_ih0 = (const float*)d_in[6];
  const float* b_hh0 = (const float*)d_in[7];
  const float* w_ih1 = (const float*)d_in[8];
  const float* w_hh1 = (const float*)d_in[9];
  const float* b_ih1 = (const float*)d_in[10];
  const float* b_hh1 = (const float*)d_in[11];
  const float* ln_g  = (const float*)d_in[12];
  const float* ln_b  = (const float*)d_in[13];
  const float* w1    = (const float*)d_in[14];
  const float* b1    = (const float*)d_in[15];
  const float* w2    = (const float*)d_in[16];
  const float* b2    = (const float*)d_in[17];
  float* out = (float*)d_out;

  // ws layout: h0ex[2][512][256] bf16 | h1ex[2][512][256] bf16 |
  //            flags0[32][256] | flags1[32][256]   (flags stride 1KB per btile)
  unsigned short* h0ex = (unsigned short*)d_ws;
  unsigned short* h1ex = h0ex + 2 * kBH;
  const size_t exch_bytes = (size_t)2 * (2 * kBH) * sizeof(unsigned short);  // 1 MiB
  int* flags0 = (int*)((char*)d_ws + exch_bytes);
  int* flags1 = flags0 + kNB * kS;
  const size_t flag_bytes = (size_t)2 * kNB * kS * sizeof(int);  // 64 KiB

  // Only flags need zeroing (exchange buffers are always written before read).
  hipMemsetAsync(flags0, 0, flag_bytes, stream);

  lstm_scan_kernel<<<dim3(kNB * kNS), dim3(256), 0, stream>>>(
      x, W_emb, b_emb, w_ih0, w_hh0, b_ih0, b_hh0, w_ih1, w_hh1, b_ih1, b_hh1,
      h0ex, h1ex, flags0, flags1, out);

  head_kernel<<<dim3(kB), dim3(64), 0, stream>>>(
      out + OUT_H + kBH, mask, ln_g, ln_b, w1, b1, w2, b2, out);
}